// Round 15
// baseline (3055.512 us; speedup 1.0000x reference)
//
#include <hip/hip_runtime.h>
#include <hip/hip_bf16.h>
#include <stdint.h>

// QuantLinear GPTQ 4-bit: out[8192,11008] = x[8192,4096] . W[4096,11008] + bias
// i8 path: W' = (q-z) exact in i8; x per-row i8; per-group(128) scales folded
// per-phase on i32 quadrant partials; row scale at epilogue.
// r15: i8 ported into the audited r5 256x256 8-phase schedule. K-tile = 128
// (= one scale group) -> 32 iterations instead of 64 at identical per-iter
// cost (LDS rows are 128 B in both bf16/BK64 and i8/BK128 -> same geometry,
// swizzle, stage slots, vmcnt ledger).
#define M_DIM 8192
#define K_DIM 4096
#define N_DIM 11008

typedef int i32x4 __attribute__((ext_vector_type(4)));
typedef float f32x4 __attribute__((ext_vector_type(4)));

typedef __attribute__((address_space(1))) const void global_cvoid;
typedef __attribute__((address_space(3))) void lds_void;

__device__ __forceinline__ void gload_lds16(const void* g, void* l) {
  // async global->LDS: each lane's 16B lands at lds_base + lane*16 (linear dest)
  __builtin_amdgcn_global_load_lds((global_cvoid*)g, (lds_void*)l, 16, 0, 0);
}

// ---------------- fused prep: quantize x (blocks < 8192) | unpack W (rest) ----------------
__global__ void k_prep(const float* __restrict__ x, signed char* __restrict__ xq,
                       float* __restrict__ sx, const int* __restrict__ qw,
                       const int* __restrict__ qz, signed char* __restrict__ wt) {
  if (blockIdx.x < M_DIM) {
    int m = blockIdx.x;
    int tx = threadIdx.x;                     // 256 threads, 16 floats each
    const float4* row = (const float4*)(x + (size_t)m * K_DIM);
    float4 v[4];
    float mx = 0.f;
    #pragma unroll
    for (int i = 0; i < 4; ++i) {
      v[i] = row[tx * 4 + i];
      mx = fmaxf(mx, fmaxf(fmaxf(fabsf(v[i].x), fabsf(v[i].y)),
                           fmaxf(fabsf(v[i].z), fabsf(v[i].w))));
    }
    #pragma unroll
    for (int off = 1; off < 64; off <<= 1)
      mx = fmaxf(mx, __shfl_xor(mx, off));
    __shared__ float wmx[4];
    if ((tx & 63) == 0) wmx[tx >> 6] = mx;
    __syncthreads();
    mx = fmaxf(fmaxf(wmx[0], wmx[1]), fmaxf(wmx[2], wmx[3]));
    mx = fmaxf(mx, 1e-20f);
    float scale = 127.0f / mx;
    if (tx == 0) sx[m] = mx / 127.0f;
    union { signed char c[16]; uint4 u; } p;
    #pragma unroll
    for (int i = 0; i < 4; ++i) {
      p.c[i * 4 + 0] = (signed char)(int)rintf(v[i].x * scale);
      p.c[i * 4 + 1] = (signed char)(int)rintf(v[i].y * scale);
      p.c[i * 4 + 2] = (signed char)(int)rintf(v[i].z * scale);
      p.c[i * 4 + 3] = (signed char)(int)rintf(v[i].w * scale);
    }
    ((uint4*)(xq + (size_t)m * K_DIM))[tx] = p.u;
  } else {
    int b = blockIdx.x - M_DIM;               // 2752 blocks: 43 n-blk x 64 k-blk
    int n = (b % 43) * 256 + threadIdx.x;
    int k8_0 = (b / 43) * 8;
    int g = (k8_0 * 8) >> 7;
    int zq = (qz[g * (N_DIM / 8) + (n >> 3)] >> ((n & 7) * 4)) & 15;
    #pragma unroll
    for (int i = 0; i < 8; ++i) {
      int k8 = k8_0 + i;
      int w = qw[(size_t)k8 * N_DIM + n];
      union { signed char c[8]; uint2 u; } r;
      #pragma unroll
      for (int j = 0; j < 8; ++j)
        r.c[j] = (signed char)(((w >> (4 * j)) & 15) - zq);
      *(uint2*)(wt + (size_t)n * K_DIM + (size_t)k8 * 8) = r.u;
    }
  }
}

// ---------------- 256x256 8-phase i8 GEMM, BK=128 (one group per K-tile) ----------------
// 8 waves (2Mx4N), per-wave 128x64 out. LDS: sh[buf][ab][half] x 16KB = 128KiB.
// Phase q computes output quadrant rows q*32..q*32+31 over full K=128 of the
// tile (kk = K-halves, slots {fq, 4+fq}), then folds the i32 partials into
// accf with the group scale (phase-local acci -> only 32 extra regs).
// Schedule/swizzle/stage-slots/vmcnt(4) ledger identical to the audited r5
// kernel; scale loads issue at P1-top (older than P3/P4 stages -> ledger
// invariant unchanged: each vmcnt(4) leaves exactly the 2 newest stages x2).

#define MFMAQF(q, bsel) do { \
  i32x4 ac00, ac01, ac02, ac03, ac10, ac11, ac12, ac13; \
  __builtin_amdgcn_s_setprio(1); \
  ac00 = __builtin_amdgcn_mfma_i32_16x16x64_i8(af[0][0], bf[0][0], zq4, 0, 0, 0); \
  ac01 = __builtin_amdgcn_mfma_i32_16x16x64_i8(af[0][0], bf[1][0], zq4, 0, 0, 0); \
  ac02 = __builtin_amdgcn_mfma_i32_16x16x64_i8(af[0][0], bf[2][0], zq4, 0, 0, 0); \
  ac03 = __builtin_amdgcn_mfma_i32_16x16x64_i8(af[0][0], bf[3][0], zq4, 0, 0, 0); \
  ac10 = __builtin_amdgcn_mfma_i32_16x16x64_i8(af[1][0], bf[0][0], zq4, 0, 0, 0); \
  ac11 = __builtin_amdgcn_mfma_i32_16x16x64_i8(af[1][0], bf[1][0], zq4, 0, 0, 0); \
  ac12 = __builtin_amdgcn_mfma_i32_16x16x64_i8(af[1][0], bf[2][0], zq4, 0, 0, 0); \
  ac13 = __builtin_amdgcn_mfma_i32_16x16x64_i8(af[1][0], bf[3][0], zq4, 0, 0, 0); \
  ac00 = __builtin_amdgcn_mfma_i32_16x16x64_i8(af[0][1], bf[0][1], ac00, 0, 0, 0); \
  ac01 = __builtin_amdgcn_mfma_i32_16x16x64_i8(af[0][1], bf[1][1], ac01, 0, 0, 0); \
  ac02 = __builtin_amdgcn_mfma_i32_16x16x64_i8(af[0][1], bf[2][1], ac02, 0, 0, 0); \
  ac03 = __builtin_amdgcn_mfma_i32_16x16x64_i8(af[0][1], bf[3][1], ac03, 0, 0, 0); \
  ac10 = __builtin_amdgcn_mfma_i32_16x16x64_i8(af[1][1], bf[0][1], ac10, 0, 0, 0); \
  ac11 = __builtin_amdgcn_mfma_i32_16x16x64_i8(af[1][1], bf[1][1], ac11, 0, 0, 0); \
  ac12 = __builtin_amdgcn_mfma_i32_16x16x64_i8(af[1][1], bf[2][1], ac12, 0, 0, 0); \
  ac13 = __builtin_amdgcn_mfma_i32_16x16x64_i8(af[1][1], bf[3][1], ac13, 0, 0, 0); \
  __builtin_amdgcn_s_setprio(0); \
  _Pragma("unroll") \
  for (int r = 0; r < 4; ++r) { \
    accf[(q)*2+0][0][r] += sg[bsel][0] * (float)ac00[r]; \
    accf[(q)*2+0][1][r] += sg[bsel][1] * (float)ac01[r]; \
    accf[(q)*2+0][2][r] += sg[bsel][2] * (float)ac02[r]; \
    accf[(q)*2+0][3][r] += sg[bsel][3] * (float)ac03[r]; \
    accf[(q)*2+1][0][r] += sg[bsel][0] * (float)ac10[r]; \
    accf[(q)*2+1][1][r] += sg[bsel][1] * (float)ac11[r]; \
    accf[(q)*2+1][2][r] += sg[bsel][2] * (float)ac12[r]; \
    accf[(q)*2+1][3][r] += sg[bsel][3] * (float)ac13[r]; \
  } \
} while (0)

// A fragments (2 mi x 2 kk) for quadrant q of buffer buf
#define LOADA(buf, q) do { \
  const unsigned char* aa_ = sh + (((buf)*2)*2 + wm) * 16384 + (q) * 4096; \
  af[0][0] = *(const i32x4*)(const void*)(aa_ + aoff0); \
  af[0][1] = *(const i32x4*)(const void*)(aa_ + aoff1); \
  af[1][0] = *(const i32x4*)(const void*)(aa_ + 2048 + aoff0); \
  af[1][1] = *(const i32x4*)(const void*)(aa_ + 2048 + aoff1); \
} while (0)

// B fragments (4 nj x 2 kk) of buffer buf (once per tile)
#define LOADB(buf) do { \
  const unsigned char* bb_ = sh + (((buf)*2 + 1)*2 + (wn >> 1)) * 16384; \
  bf[0][0] = *(const i32x4*)(const void*)(bb_ + boff0); \
  bf[0][1] = *(const i32x4*)(const void*)(bb_ + boff1); \
  bf[1][0] = *(const i32x4*)(const void*)(bb_ + 2048 + boff0); \
  bf[1][1] = *(const i32x4*)(const void*)(bb_ + 2048 + boff1); \
  bf[2][0] = *(const i32x4*)(const void*)(bb_ + 4096 + boff0); \
  bf[2][1] = *(const i32x4*)(const void*)(bb_ + 4096 + boff1); \
  bf[3][0] = *(const i32x4*)(const void*)(bb_ + 6144 + boff0); \
  bf[3][1] = *(const i32x4*)(const void*)(bb_ + 6144 + boff1); \
} while (0)

// stage one 128-row half of A(ab=0)/B(ab=1) for K-tile kt into buffer buf
#define STAGE(buf, ab, half, kt) do { \
  const signed char* g_ = ((ab) ? pB : pA) + ((size_t)(half) * 128) * K_DIM + (size_t)(kt) * 128; \
  unsigned char* l_ = sh + ((((buf)*2 + (ab))*2 + (half)) * 16384) + w * 2048; \
  gload_lds16(g_, l_); \
  gload_lds16(g_ + 8 * (size_t)K_DIM, l_ + 1024); \
} while (0)

// group scales for tiles t (->sg[0]) and t+1 (->sg[1]), issued oldest-first
#define SCLOAD(t) do { \
  sg[0][0] = sc[(size_t)(t) * N_DIM + c0 +  0]; \
  sg[0][1] = sc[(size_t)(t) * N_DIM + c0 + 16]; \
  sg[0][2] = sc[(size_t)(t) * N_DIM + c0 + 32]; \
  sg[0][3] = sc[(size_t)(t) * N_DIM + c0 + 48]; \
  sg[1][0] = sc[(size_t)(t + 1) * N_DIM + c0 +  0]; \
  sg[1][1] = sc[(size_t)(t + 1) * N_DIM + c0 + 16]; \
  sg[1][2] = sc[(size_t)(t + 1) * N_DIM + c0 + 32]; \
  sg[1][3] = sc[(size_t)(t + 1) * N_DIM + c0 + 48]; \
} while (0)

#define NOSTMT ((void)0)
#define WAIT_VM4 asm volatile("s_waitcnt vmcnt(4)" ::: "memory")
#define WAIT_VM0 asm volatile("s_waitcnt vmcnt(0)" ::: "memory")

// r5 phase: [scales] -> reads -> stage -> lgkm drain -> 16 MFMA + fold -> [vmcnt] -> barrier
#define PHASE(buf, q, DOB, TOP, S1, VW) do { \
  TOP; \
  LOADA(buf, q); \
  if (DOB) LOADB(buf); \
  S1; \
  asm volatile("s_waitcnt lgkmcnt(0)" ::: "memory"); \
  __builtin_amdgcn_sched_barrier(0); \
  MFMAQF(q, buf); \
  VW; \
  __builtin_amdgcn_s_barrier(); \
  asm volatile("" ::: "memory"); \
} while (0)

__global__ __launch_bounds__(512, 2) void k_gemm8(const signed char* __restrict__ xq,
                                                  const signed char* __restrict__ wq,
                                                  const float* __restrict__ sc,
                                                  const float* __restrict__ sx,
                                                  const float* __restrict__ bias,
                                                  float* __restrict__ out) {
  __shared__ __align__(16) unsigned char sh[2 * 2 * 2 * 16384];  // 128 KiB

  const int nwg = gridDim.x;                 // 1376, % 8 == 0 -> bijective
  int bid = blockIdx.x;
  int swz = (bid & 7) * (nwg >> 3) + (bid >> 3);
  const int ntn = N_DIM / 256;               // 43
  int mt = swz / ntn;
  int nt = swz % ntn;

  const int tid = threadIdx.x;
  const int w = tid >> 6;        // wave 0..7
  const int lane = tid & 63;
  const int wm = w >> 2;         // 0..1 (M sub-tile 128)
  const int wn = w & 3;          // 0..3 (N sub-tile 64)
  const int fr = lane & 15;
  const int fq = lane >> 4;
  const int r7 = fr & 7;

  // staging: per-lane pre-swizzled global source (involution slot^row), 128B rows
  const int srow = lane >> 3;                 // 0..7
  const int sslot = (lane & 7) ^ srow;        // 16B slot in the 128B row
  const size_t goff = (size_t)srow * K_DIM + (size_t)sslot * 16;
  const signed char* pA = xq + (size_t)(mt * 256 + w * 16) * K_DIM + goff;
  const signed char* pB = wq + (size_t)(nt * 256 + w * 16) * K_DIM + goff;

  // fragment byte offsets: row*128 + (slot ^ r7)*16, slots {fq, 4+fq}
  const int aoff0 = fr * 128 + ((fq) ^ r7) * 16;
  const int aoff1 = fr * 128 + ((4 + fq) ^ r7) * 16;
  const int boff0 = ((wn & 1) * 64 + fr) * 128 + ((fq) ^ r7) * 16;
  const int boff1 = ((wn & 1) * 64 + fr) * 128 + ((4 + fq) ^ r7) * 16;

  const int c0 = nt * 256 + wn * 64 + fr;    // this lane's base output column

  f32x4 accf[8][4] = {};
  i32x4 af[2][2];
  i32x4 bf[4][2];
  float sg[2][4];
  const i32x4 zq4 = {0, 0, 0, 0};

  // prologue: tile0 fully (buf0, 8 gloads), tile1 B-halves (buf1, 4 gloads)
  STAGE(0, 0, 0, 0); STAGE(0, 0, 1, 0); STAGE(0, 1, 0, 0); STAGE(0, 1, 1, 0);
  STAGE(1, 1, 0, 1); STAGE(1, 1, 1, 1);
  WAIT_VM4;                       // tile0's 8 done; B(1) x4 in flight
  __builtin_amdgcn_s_barrier();
  asm volatile("" ::: "memory");

  // main loop: iteration computes K-tiles 2i (buf0, P1-4) and 2i+1 (buf1, P5-8)
  for (int i = 0; i < 15; ++i) {
    int t = 2 * i;
    PHASE(0, 0, true,  SCLOAD(t), STAGE(1, 0, 0, t + 1), NOSTMT);   // P1
    PHASE(0, 1, false, NOSTMT,    STAGE(1, 0, 1, t + 1), NOSTMT);   // P2
    PHASE(0, 2, false, NOSTMT,    STAGE(0, 1, 0, t + 2), NOSTMT);   // P3
    PHASE(0, 3, false, NOSTMT,    STAGE(0, 1, 1, t + 2), WAIT_VM4); // P4
    PHASE(1, 0, true,  NOSTMT,    STAGE(0, 0, 0, t + 2), NOSTMT);   // P5
    PHASE(1, 1, false, NOSTMT,    STAGE(0, 0, 1, t + 2), NOSTMT);   // P6
    PHASE(1, 2, false, NOSTMT,    STAGE(1, 1, 0, t + 3), NOSTMT);   // P7
    PHASE(1, 3, false, NOSTMT,    STAGE(1, 1, 1, t + 3), WAIT_VM4); // P8
  }
  // tail: tiles 30 (buf0), 31 (buf1)
  PHASE(0, 0, true,  SCLOAD(30), STAGE(1, 0, 0, 31), NOSTMT);
  PHASE(0, 1, false, NOSTMT,     STAGE(1, 0, 1, 31), NOSTMT);
  PHASE(0, 2, false, NOSTMT,     NOSTMT,             NOSTMT);
  PHASE(0, 3, false, NOSTMT,     NOSTMT,             WAIT_VM0);
  PHASE(1, 0, true,  NOSTMT,     NOSTMT,             NOSTMT);
  PHASE(1, 1, false, NOSTMT,     NOSTMT,             NOSTMT);
  PHASE(1, 2, false, NOSTMT,     NOSTMT,             NOSTMT);
  PHASE(1, 3, false, NOSTMT,     NOSTMT,             NOSTMT);

  // epilogue: C/D layout col=lane&15, row=(lane>>4)*4+reg; out = sx[m]*accf + bias
  const int r0 = mt * 256 + wm * 128 + fq * 4;
  #pragma unroll
  for (int mi = 0; mi < 8; ++mi) {
    float sxr[4];
    #pragma unroll
    for (int r = 0; r < 4; ++r) sxr[r] = sx[r0 + mi * 16 + r];
    #pragma unroll
    for (int nj = 0; nj < 4; ++nj) {
      int col = c0 + nj * 16;
      float bv = bias[col];
      size_t base = (size_t)(r0 + mi * 16) * N_DIM + col;
      #pragma unroll
      for (int r = 0; r < 4; ++r)
        out[base + (size_t)r * N_DIM] = sxr[r] * accf[mi][nj][r] + bv;
    }
  }
}

// ---------------- fallback (ws too small): naive fp32 ----------------
__global__ void k_fallback(const float* __restrict__ x, const int* __restrict__ qw,
                           const int* __restrict__ qz, const float* __restrict__ sc,
                           const float* __restrict__ bias, float* __restrict__ out) {
  int n = blockIdx.x * blockDim.x + threadIdx.x;
  int m = blockIdx.y;
  const float* xr = x + (size_t)m * K_DIM;
  float acc = 0.f;
  for (int g = 0; g < 32; ++g) {
    float s = sc[g * N_DIM + n];
    int zq = (qz[g * (N_DIM / 8) + (n >> 3)] >> ((n & 7) * 4)) & 15;
    float zs = s * (float)zq;
    for (int k8 = g * 16; k8 < g * 16 + 16; ++k8) {
      int w = qw[(size_t)k8 * N_DIM + n];
      #pragma unroll
      for (int j = 0; j < 8; ++j) {
        float wf = s * (float)((w >> (4 * j)) & 15) - zs;
        acc += wf * xr[k8 * 8 + j];
      }
    }
  }
  out[(size_t)m * N_DIM + n] = acc + bias[n];
}

extern "C" void kernel_launch(void* const* d_in, const int* in_sizes, int n_in,
                              void* d_out, int out_size, void* d_ws, size_t ws_size,
                              hipStream_t stream) {
  const float* x  = (const float*)d_in[0];
  const int* qw   = (const int*)d_in[1];
  const int* qz   = (const int*)d_in[2];
  const float* sc = (const float*)d_in[3];
  const float* bias = (const float*)d_in[4];
  float* out = (float*)d_out;

  const size_t xq_bytes = (size_t)M_DIM * K_DIM;          // 33,554,432
  const size_t sx_bytes = (size_t)M_DIM * sizeof(float);  // 32,768
  const size_t wq_bytes = (size_t)N_DIM * K_DIM;          // 45,088,768
  const size_t need = xq_bytes + sx_bytes + wq_bytes;

  if (ws_size >= need) {
    signed char* xq = (signed char*)d_ws;
    float* sx = (float*)((char*)d_ws + xq_bytes);
    signed char* wq = (signed char*)((char*)d_ws + xq_bytes + sx_bytes);
    k_prep<<<dim3(M_DIM + 2752), dim3(256), 0, stream>>>(x, xq, sx, qw, qz, wq);
    k_gemm8<<<dim3((M_DIM / 256) * (N_DIM / 256)), dim3(512), 0, stream>>>(xq, wq, sc, sx, bias, out);
  } else {
    k_fallback<<<dim3(N_DIM / 256, M_DIM), dim3(256), 0, stream>>>(x, qw, qz, sc, bias, out);
  }
}